// Round 4
// baseline (157.211 us; speedup 1.0000x reference)
//
#include <hip/hip_runtime.h>
#include <math.h>

#define C_  2000
#define B_  4096
#define KK  3
#define SLOT_CAP 256      // compact gather capacity (actual nmin ~80)
#define K3B 1024          // k3 grid / ticket total (worst-case nmin <= 1024)

// k0 (counts) grid
#define K0_NXB 8
#define K0_NCH 64
#define K0_RPC (B_ / K0_NCH)   // 64 rows/chunk
#define K0_RPS (K0_RPC / 4)    // 16 rows/thread

// k1 (bce+gather) grid
#define NXB 8
#define NCH 128
#define RPC (B_ / NCH)         // 32
#define RPS (RPC / 4)          // 8

typedef unsigned long long u64;
typedef unsigned int u32;

// ---- workspace layout (bytes) ----
constexpr size_t OFF_ACC    = 0;                      // double[3]: bce, dp, dn
constexpr size_t OFF_DONE   = 24;                     // int ticket
constexpr size_t OFF_NMIN   = 28;                     // int
constexpr size_t OFF_COUNTS = 32;                     // int[C_]
constexpr size_t ZERO_BYTES = OFF_COUNTS + 4*(size_t)C_;        // 8032
constexpr size_t OFF_MLIST  = (ZERO_BYTES + 63) & ~(size_t)63;  // int[K3B]
constexpr size_t OFF_C2S    = OFF_MLIST + 4*(size_t)K3B;        // int[C_]
constexpr size_t OFF_CMP    = (OFF_C2S + 4*(size_t)C_ + 255) & ~(size_t)255;
// cmp: float[SLOT_CAP][B_] = 4 MB; total ~4.2 MB

// branchless keep-4-smallest u64 keys (ascending); ~0ull is a no-op insert
__device__ __forceinline__ u64 umin64(u64 a, u64 b) { return a < b ? a : b; }
__device__ __forceinline__ u64 umax64(u64 a, u64 b) { return a < b ? b : a; }
__device__ __forceinline__ void pins(u64* k, u64 e) {
    k[3] = umin64(k[3], umax64(k[2], e));
    k[2] = umin64(k[2], umax64(k[1], e));
    k[1] = umin64(k[1], umax64(k[0], e));
    k[0] = umin64(k[0], e);
}
// branchless keep-3-smallest floats; +INF is a no-op
__device__ __forceinline__ void nins(float* n, float e) {
    n[2] = fminf(n[2], fmaxf(n[1], e));
    n[1] = fminf(n[1], fmaxf(n[0], e));
    n[0] = fminf(n[0], e);
}

// Pass 0: per-class positive counts from target only (coalesced float4).
__global__ __launch_bounds__(256) void k0_counts(
        const float* __restrict__ target, int* __restrict__ counts)
{
    __shared__ int lnp[256];
    const int tid = threadIdx.x;
    lnp[tid] = 0;
    __syncthreads();
    const int g = tid & 63, s = tid >> 6;
    const int cb = blockIdx.x * 256 + g * 4;
    const int r0 = blockIdx.y * K0_RPC + s * K0_RPS;
    if (cb < C_) {
        const float4* tg4 = reinterpret_cast<const float4*>(target);
        const size_t base4 = ((size_t)r0 * C_ + cb) >> 2;
        int np0 = 0, np1 = 0, np2 = 0, np3 = 0;
        #pragma unroll
        for (int k = 0; k < K0_RPS; ++k) {
            float4 t4 = tg4[base4 + (size_t)k * (C_ / 4)];
            np0 += (t4.x == 1.0f); np1 += (t4.y == 1.0f);
            np2 += (t4.z == 1.0f); np3 += (t4.w == 1.0f);
        }
        atomicAdd(&lnp[g * 4 + 0], np0);
        atomicAdd(&lnp[g * 4 + 1], np1);
        atomicAdd(&lnp[g * 4 + 2], np2);
        atomicAdd(&lnp[g * 4 + 3], np3);
    }
    __syncthreads();
    int cidx = blockIdx.x * 256 + tid;
    if (cidx < C_ && lnp[tid] != 0) atomicAdd(&counts[cidx], lnp[tid]);
}

// Minority selection (stable-sort semantics without sorting):
// inclusive cumsum at class c = sum(counts<cc) + cc * #{j<=c: counts[j]==cc}.
// One wave per class; counts staged in LDS. Emits mlist + nmin + cls->slot map.
__global__ __launch_bounds__(256) void k2_minority(
        const int* __restrict__ counts, int* __restrict__ mlist,
        int* __restrict__ nmin, int* __restrict__ cls2slot)
{
    __shared__ int lc[C_];
    for (int j = threadIdx.x; j < C_; j += 256) lc[j] = counts[j];
    __syncthreads();
    int w = threadIdx.x >> 6, lane = threadIdx.x & 63;
    int ci = blockIdx.x * 4 + w;              // grid 500*4 = 2000 exact
    int cc = lc[ci];
    int sless = 0, tcnt = 0;
    #pragma unroll 4
    for (int j = lane; j < C_; j += 64) {
        int cj = lc[j];
        sless += (cj < cc) ? cj : 0;
        tcnt  += (cj == cc && j <= ci) ? 1 : 0;
    }
    #pragma unroll
    for (int off = 32; off > 0; off >>= 1) {
        sless += __shfl_down(sless, off);
        tcnt  += __shfl_down(tcnt, off);
    }
    if (lane == 0) {
        int slot = -1;
        if (cc > 1 && (sless + cc * tcnt) <= (B_ / 2)) {
            slot = atomicAdd(nmin, 1);
            mlist[slot] = ci;
        }
        cls2slot[ci] = (slot >= 0 && slot < SLOT_CAP) ? slot : -1;
    }
}

// Pass 1 (full data): BCE sum + compact gather of signed preds for minority
// classes. One pred computation site -> no cross-kernel bit-match concerns.
__global__ __launch_bounds__(256) void k1_bce_gather(
        const float* __restrict__ input, const float* __restrict__ target,
        const int* __restrict__ cls2slot, float* __restrict__ cmp,
        double* __restrict__ acc)
{
    __shared__ double lb[4];
    const int tid = threadIdx.x;
    const int g = tid & 63, s = tid >> 6;
    const int cb = blockIdx.x * 256 + g * 4;
    const int r0 = blockIdx.y * RPC + s * RPS;
    double bce = 0.0;
    if (cb < C_) {
        const int s0 = cls2slot[cb + 0], s1 = cls2slot[cb + 1];
        const int s2 = cls2slot[cb + 2], s3 = cls2slot[cb + 3];
        const float4* in4 = reinterpret_cast<const float4*>(input);
        const float4* tg4 = reinterpret_cast<const float4*>(target);
        const size_t base4 = ((size_t)r0 * C_ + cb) >> 2;
        #pragma unroll
        for (int k = 0; k < RPS; ++k) {
            size_t idx4 = base4 + (size_t)k * (C_ / 4);
            float4 x4 = in4[idx4];
            float4 t4 = tg4[idx4];
            int row = r0 + k;
            float e0 = __expf(-fabsf(x4.x)), e1 = __expf(-fabsf(x4.y));
            float e2 = __expf(-fabsf(x4.z)), e3 = __expf(-fabsf(x4.w));
            float b0 = fmaxf(x4.x, 0.0f) + __logf(1.0f + e0) - x4.x * t4.x;
            float b1 = fmaxf(x4.y, 0.0f) + __logf(1.0f + e1) - x4.y * t4.y;
            float b2 = fmaxf(x4.z, 0.0f) + __logf(1.0f + e2) - x4.z * t4.z;
            float b3 = fmaxf(x4.w, 0.0f) + __logf(1.0f + e3) - x4.w * t4.w;
            bce += (double)((b0 + b1) + (b2 + b3));
            if (s0 >= 0) { float q = 1.0f / (1.0f + e0);
                float p = (x4.x >= 0.0f) ? q : e0 * q;
                cmp[(size_t)s0 * B_ + row] = (t4.x == 1.0f) ? p : -p; }
            if (s1 >= 0) { float q = 1.0f / (1.0f + e1);
                float p = (x4.y >= 0.0f) ? q : e1 * q;
                cmp[(size_t)s1 * B_ + row] = (t4.y == 1.0f) ? p : -p; }
            if (s2 >= 0) { float q = 1.0f / (1.0f + e2);
                float p = (x4.z >= 0.0f) ? q : e2 * q;
                cmp[(size_t)s2 * B_ + row] = (t4.z == 1.0f) ? p : -p; }
            if (s3 >= 0) { float q = 1.0f / (1.0f + e3);
                float p = (x4.w >= 0.0f) ? q : e3 * q;
                cmp[(size_t)s3 * B_ + row] = (t4.w == 1.0f) ? p : -p; }
        }
    }
    #pragma unroll
    for (int off = 32; off > 0; off >>= 1) bce += __shfl_down(bce, off);
    if (g == 0) lb[s] = bce;
    __syncthreads();
    if (tid == 0) atomicAdd(&acc[0], lb[0] + lb[1] + lb[2] + lb[3]);
}

// Anchor pass + finalize: one block per minority slot; reads its COMPACT
// column (16 KB, coalesced, L2-warm). Last ticket block writes the scalar.
__global__ __launch_bounds__(256) void k3_anchor_final(
        const float* __restrict__ input, const float* __restrict__ target,
        const int* __restrict__ counts, const int* __restrict__ mlist,
        const int* __restrict__ nmin, const float* __restrict__ cmp,
        double* __restrict__ acc, int* __restrict__ done, float* __restrict__ out)
{
    __shared__ float sval[B_];        // 16 KB: +pred if positive, -pred if negative
    __shared__ u64   lpk[4][4];
    __shared__ float lnv[4][3];
    __shared__ double lred[4][2];
    const int tid = threadIdx.x;
    const int w = tid >> 6, lane = tid & 63;
    const int nm = *nmin;

    if (blockIdx.x < nm) {
        const int c = mlist[blockIdx.x];
        u64   pk[4] = {~0ull, ~0ull, ~0ull, ~0ull};
        float nv[3] = {INFINITY, INFINITY, INFINITY};
        if (blockIdx.x < SLOT_CAP) {
            const float* col = cmp + (size_t)blockIdx.x * B_;
            #pragma unroll 4
            for (int i = tid; i < B_; i += 256) {
                float sv = col[i];
                sval[i] = sv;
                bool pos = (sv > 0.0f);
                float pred = fabsf(sv);
                pins(pk, pos ? ((((u64)__float_as_uint(pred)) << 32) | (u32)i) : ~0ull);
                nins(nv, pos ? INFINITY : pred);
            }
        } else {
            // defensive overflow path (nmin > SLOT_CAP): strided direct scan
            #pragma unroll 4
            for (int i = tid; i < B_; i += 256) {
                float x = input[(size_t)i * C_ + c];
                float t = target[(size_t)i * C_ + c];
                float e2 = __expf(-fabsf(x));
                float q  = 1.0f / (1.0f + e2);
                float pred = (x >= 0.0f) ? q : e2 * q;
                bool pos = (t == 1.0f);
                sval[i] = pos ? pred : -pred;
                pins(pk, pos ? ((((u64)__float_as_uint(pred)) << 32) | (u32)i) : ~0ull);
                nins(nv, pos ? INFINITY : pred);
            }
        }
        #pragma unroll
        for (int off = 32; off > 0; off >>= 1) {
            u64 o0 = __shfl_down(pk[0], off), o1 = __shfl_down(pk[1], off);
            u64 o2 = __shfl_down(pk[2], off), o3 = __shfl_down(pk[3], off);
            float f0 = __shfl_down(nv[0], off), f1 = __shfl_down(nv[1], off);
            float f2 = __shfl_down(nv[2], off);
            pins(pk, o0); pins(pk, o1); pins(pk, o2); pins(pk, o3);
            nins(nv, f0); nins(nv, f1); nins(nv, f2);
        }
        if (lane == 0) {
            #pragma unroll
            for (int q2 = 0; q2 < 4; ++q2) lpk[w][q2] = pk[q2];
            #pragma unroll
            for (int q2 = 0; q2 < 3; ++q2) lnv[w][q2] = nv[q2];
        }
        __syncthreads();
        u64   fk[4] = {~0ull, ~0ull, ~0ull, ~0ull};
        float fn[3] = {INFINITY, INFINITY, INFINITY};
        #pragma unroll
        for (int w2 = 0; w2 < 4; ++w2) {
            #pragma unroll
            for (int q2 = 0; q2 < 4; ++q2) pins(fk, lpk[w2][q2]);
            #pragma unroll
            for (int q2 = 0; q2 < 3; ++q2) nins(fn, lnv[w2][q2]);
        }
        const int np = counts[c];
        const int m  = min(KK, max(np - 1, 0));
        const int nn = min(KK, B_ - np);
        float pv[4];
        #pragma unroll
        for (int q2 = 0; q2 < 4; ++q2) pv[q2] = __uint_as_float((u32)(fk[q2] >> 32));
        // sentinel slots are provably never read: dpos touches first m (<= np-1)
        // non-self entries; dneg first nn (<= #negatives).
        double dp = 0.0, dn = 0.0;
        for (int i = tid; i < B_; i += 256) {
            float sv = sval[i];
            if (sv > 0.0f) {                        // anchor (minority positive)
                float pred = sv;
                u64 key = (((u64)__float_as_uint(pred)) << 32) | (u32)i;
                int r = -1;
                #pragma unroll
                for (int q2 = 0; q2 < 4; ++q2) if (fk[q2] == key) r = q2;
                float dpos = 0.0f;
                if (r < 0) {
                    for (int j = 0; j < m; ++j) dpos += fabsf(pred - pv[j]);
                } else {
                    int cnt = 0;
                    #pragma unroll
                    for (int j = 0; j < 4; ++j) {
                        if (j != r && cnt < m) { dpos += fabsf(pred - pv[j]); cnt++; }
                    }
                }
                float dneg = 0.0f;
                for (int l = 0; l < nn; ++l) dneg += fabsf(pred - fn[l]);
                dp += (double)nn * (double)dpos;
                dn += (double)m  * (double)dneg;
            }
        }
        #pragma unroll
        for (int off = 32; off > 0; off >>= 1) {
            dp += __shfl_down(dp, off);
            dn += __shfl_down(dn, off);
        }
        if (lane == 0) { lred[w][0] = dp; lred[w][1] = dn; }
        __syncthreads();
        if (tid == 0) {
            atomicAdd(&acc[1], lred[0][0] + lred[1][0] + lred[2][0] + lred[3][0]);
            atomicAdd(&acc[2], lred[0][1] + lred[1][1] + lred[2][1] + lred[3][1]);
        }
    }
    // ticket: every block participates; last one finalizes the scalar
    if (tid == 0) {
        __threadfence();
        int old = atomicAdd(done, 1);
        if (old == K3B - 1) {
            double b   = atomicAdd(&acc[0], 0.0);
            double dpv = atomicAdd(&acc[1], 0.0);
            double dnv = atomicAdd(&acc[2], 0.0);
            double bce = b / ((double)B_ * (double)C_);
            double crl = dpv - dnv + 1.0;           // MARGIN
            if (crl < 0.0) crl = 0.0;
            out[0] = (float)(0.001 * crl + 0.999 * bce);  // ALPHA, 1-ALPHA
        }
    }
}

extern "C" void kernel_launch(void* const* d_in, const int* in_sizes, int n_in,
                              void* d_out, int out_size, void* d_ws, size_t ws_size,
                              hipStream_t stream) {
    const float* input  = (const float*)d_in[0];
    const float* target = (const float*)d_in[1];
    // d_in[2] (X) does not affect the reference output.
    float* out = (float*)d_out;
    char* ws = (char*)d_ws;

    double* acc    = (double*)(ws + OFF_ACC);
    int*    done   = (int*)   (ws + OFF_DONE);
    int*    nmin   = (int*)   (ws + OFF_NMIN);
    int*    counts = (int*)   (ws + OFF_COUNTS);
    int*    mlist  = (int*)   (ws + OFF_MLIST);
    int*    c2s    = (int*)   (ws + OFF_C2S);
    float*  cmp    = (float*) (ws + OFF_CMP);

    hipMemsetAsync(ws, 0, ZERO_BYTES, stream);   // acc + done + nmin + counts

    k0_counts<<<dim3(K0_NXB, K0_NCH), 256, 0, stream>>>(target, counts);
    k2_minority<<<C_ / 4, 256, 0, stream>>>(counts, mlist, nmin, c2s);
    k1_bce_gather<<<dim3(NXB, NCH), 256, 0, stream>>>(input, target, c2s, cmp, acc);
    k3_anchor_final<<<K3B, 256, 0, stream>>>(input, target, counts, mlist, nmin,
                                             cmp, acc, done, out);
}

// Round 5
// 133.431 us; speedup vs baseline: 1.1782x; 1.1782x over previous
//
#include <hip/hip_runtime.h>
#include <math.h>

#define C_  2000
#define B_  4096
#define KK  3
#define K3G 128                // k3 grid (slot-strided; nmin worst-case 1024)
#define NMAX 1024              // max possible minority classes (each has >=2 pos)

// k1 grid
#define NXB 8                  // 8*256 = 2048 class lanes >= 2000
#define NCH 64                 // row chunks
#define RPC (B_ / NCH)         // 64 rows per block
#define RPS (RPC / 4)          // 16 rows per thread (4 waves = 4 row splits)

typedef unsigned long long u64;
typedef unsigned int u32;

// ---- workspace layout (bytes) ----
constexpr size_t OFF_NMIN   = 0;                                  // int
constexpr size_t OFF_COUNTS = 64;                                 // int[C_]
constexpr size_t ZERO_BYTES = OFF_COUNTS + 4*(size_t)C_;          // 8064 — one memset
constexpr size_t OFF_MLIST  = (ZERO_BYTES + 63) & ~(size_t)63;    // int[NMAX]
constexpr size_t OFF_BCEP   = (OFF_MLIST + 4*(size_t)NMAX + 63) & ~(size_t)63; // double[512]
constexpr size_t OFF_DPP    = OFF_BCEP + 8*512;                   // double[NMAX]
constexpr size_t OFF_DNP    = OFF_DPP  + 8*(size_t)NMAX;          // double[NMAX]

// branchless keep-4-smallest u64 keys (ascending); ~0ull is a no-op insert
__device__ __forceinline__ u64 umin64(u64 a, u64 b) { return a < b ? a : b; }
__device__ __forceinline__ u64 umax64(u64 a, u64 b) { return a < b ? b : a; }
__device__ __forceinline__ void pins(u64* k, u64 e) {
    k[3] = umin64(k[3], umax64(k[2], e));
    k[2] = umin64(k[2], umax64(k[1], e));
    k[1] = umin64(k[1], umax64(k[0], e));
    k[0] = umin64(k[0], e);
}
// branchless keep-3-smallest floats; +INF is a no-op
__device__ __forceinline__ void nins(float* n, float e) {
    n[2] = fminf(n[2], fmaxf(n[1], e));
    n[1] = fminf(n[1], fmaxf(n[0], e));
    n[0] = fminf(n[0], e);
}

// Pass 1 — the ONLY full-data pass: BCE partial (plain store per block, no
// atomic contention) + per-class positive counts (distributed atomics).
__global__ __launch_bounds__(256) void k1_bce_counts(
        const float* __restrict__ input, const float* __restrict__ target,
        int* __restrict__ counts, double* __restrict__ bcep)
{
    __shared__ int lnp[256];
    __shared__ double lb[4];
    const int tid = threadIdx.x;
    lnp[tid] = 0;
    __syncthreads();

    const int g = tid & 63, s = tid >> 6;
    const int cb = blockIdx.x * 256 + g * 4;
    const int r0 = blockIdx.y * RPC + s * RPS;
    double bce = 0.0;
    if (cb < C_) {
        const float4* in4 = reinterpret_cast<const float4*>(input);
        const float4* tg4 = reinterpret_cast<const float4*>(target);
        const size_t base4 = ((size_t)r0 * C_ + cb) >> 2;
        int np0 = 0, np1 = 0, np2 = 0, np3 = 0;
        #pragma unroll 4
        for (int k = 0; k < RPS; ++k) {
            size_t idx4 = base4 + (size_t)k * (C_ / 4);
            float4 x4 = in4[idx4];
            float4 t4 = tg4[idx4];
            float e0 = __expf(-fabsf(x4.x)), e1 = __expf(-fabsf(x4.y));
            float e2 = __expf(-fabsf(x4.z)), e3 = __expf(-fabsf(x4.w));
            float b0 = fmaxf(x4.x, 0.0f) + __logf(1.0f + e0) - x4.x * t4.x;
            float b1 = fmaxf(x4.y, 0.0f) + __logf(1.0f + e1) - x4.y * t4.y;
            float b2 = fmaxf(x4.z, 0.0f) + __logf(1.0f + e2) - x4.z * t4.z;
            float b3 = fmaxf(x4.w, 0.0f) + __logf(1.0f + e3) - x4.w * t4.w;
            bce += (double)((b0 + b1) + (b2 + b3));
            np0 += (t4.x == 1.0f); np1 += (t4.y == 1.0f);
            np2 += (t4.z == 1.0f); np3 += (t4.w == 1.0f);
        }
        atomicAdd(&lnp[g * 4 + 0], np0);
        atomicAdd(&lnp[g * 4 + 1], np1);
        atomicAdd(&lnp[g * 4 + 2], np2);
        atomicAdd(&lnp[g * 4 + 3], np3);
    }
    #pragma unroll
    for (int off = 32; off > 0; off >>= 1) bce += __shfl_down(bce, off);
    if (g == 0) lb[s] = bce;
    __syncthreads();
    if (tid == 0)
        bcep[blockIdx.y * NXB + blockIdx.x] = lb[0] + lb[1] + lb[2] + lb[3];
    int cidx = blockIdx.x * 256 + tid;
    if (cidx < C_ && lnp[tid] != 0) atomicAdd(&counts[cidx], lnp[tid]);
}

// Minority selection (stable-sort semantics without sorting):
// inclusive cumsum at class c = sum(counts<cc) + cc * #{j<=c: counts[j]==cc}.
// One wave per class; counts staged in LDS. Emits compacted mlist + nmin.
__global__ __launch_bounds__(256) void k2_minority(
        const int* __restrict__ counts, int* __restrict__ mlist, int* __restrict__ nmin)
{
    __shared__ int lc[C_];
    for (int j = threadIdx.x; j < C_; j += 256) lc[j] = counts[j];
    __syncthreads();
    int w = threadIdx.x >> 6, lane = threadIdx.x & 63;
    int ci = blockIdx.x * 4 + w;              // grid 500*4 = 2000 exact
    int cc = lc[ci];
    int sless = 0, tcnt = 0;
    #pragma unroll 4
    for (int j = lane; j < C_; j += 64) {
        int cj = lc[j];
        sless += (cj < cc) ? cj : 0;
        tcnt  += (cj == cc && j <= ci) ? 1 : 0;
    }
    #pragma unroll
    for (int off = 32; off > 0; off >>= 1) {
        sless += __shfl_down(sless, off);
        tcnt  += __shfl_down(tcnt, off);
    }
    if (lane == 0) {
        if (cc > 1 && (sless + cc * tcnt) <= (B_ / 2)) {
            int idx = atomicAdd(nmin, 1);
            mlist[idx] = ci;
        }
    }
}

// Anchor pass: 128 blocks slot-stride over the ~80 minority classes. Each
// block scans its class column (LLC-warm), block-merges exact (pred,row)
// top-4 positives + top-3 negatives, computes dp/dn, stores per-slot doubles.
// NO fence, NO ticket, NO atomics.
__global__ __launch_bounds__(256) void k3_anchor(
        const float* __restrict__ input, const float* __restrict__ target,
        const int* __restrict__ counts, const int* __restrict__ mlist,
        const int* __restrict__ nmin,
        double* __restrict__ dpp, double* __restrict__ dnp)
{
    __shared__ float sval[B_];        // 16 KB: +pred if positive, -pred if negative
    __shared__ u64   lpk[4][4];
    __shared__ float lnv[4][3];
    __shared__ double lred[4][2];
    const int tid = threadIdx.x;
    const int w = tid >> 6, lane = tid & 63;
    const int nm = *nmin;

    for (int slot = blockIdx.x; slot < nm; slot += K3G) {
        const int c = mlist[slot];
        u64   pk[4] = {~0ull, ~0ull, ~0ull, ~0ull};
        float nv[3] = {INFINITY, INFINITY, INFINITY};
        #pragma unroll 4
        for (int i = tid; i < B_; i += 256) {
            float x = input[(size_t)i * C_ + c];
            float t = target[(size_t)i * C_ + c];
            float e2 = __expf(-fabsf(x));
            float q  = 1.0f / (1.0f + e2);
            float pred = (x >= 0.0f) ? q : e2 * q;   // pred in (0,1), never 0
            bool pos = (t == 1.0f);
            sval[i] = pos ? pred : -pred;
            pins(pk, pos ? ((((u64)__float_as_uint(pred)) << 32) | (u32)i) : ~0ull);
            nins(nv, pos ? INFINITY : pred);
        }
        #pragma unroll
        for (int off = 32; off > 0; off >>= 1) {
            u64 o0 = __shfl_down(pk[0], off), o1 = __shfl_down(pk[1], off);
            u64 o2 = __shfl_down(pk[2], off), o3 = __shfl_down(pk[3], off);
            float f0 = __shfl_down(nv[0], off), f1 = __shfl_down(nv[1], off);
            float f2 = __shfl_down(nv[2], off);
            pins(pk, o0); pins(pk, o1); pins(pk, o2); pins(pk, o3);
            nins(nv, f0); nins(nv, f1); nins(nv, f2);
        }
        if (lane == 0) {
            #pragma unroll
            for (int q2 = 0; q2 < 4; ++q2) lpk[w][q2] = pk[q2];
            #pragma unroll
            for (int q2 = 0; q2 < 3; ++q2) lnv[w][q2] = nv[q2];
        }
        __syncthreads();
        u64   fk[4] = {~0ull, ~0ull, ~0ull, ~0ull};
        float fn[3] = {INFINITY, INFINITY, INFINITY};
        #pragma unroll
        for (int w2 = 0; w2 < 4; ++w2) {
            #pragma unroll
            for (int q2 = 0; q2 < 4; ++q2) pins(fk, lpk[w2][q2]);
            #pragma unroll
            for (int q2 = 0; q2 < 3; ++q2) nins(fn, lnv[w2][q2]);
        }
        const int np = counts[c];
        const int m  = min(KK, max(np - 1, 0));
        const int nn = min(KK, B_ - np);
        float pv[4];
        #pragma unroll
        for (int q2 = 0; q2 < 4; ++q2) pv[q2] = __uint_as_float((u32)(fk[q2] >> 32));
        // sentinel slots provably never read: dpos touches first m (<= np-1)
        // non-self entries; dneg first nn (<= #negatives).
        double dp = 0.0, dn = 0.0;
        for (int i = tid; i < B_; i += 256) {
            float sv = sval[i];
            if (sv > 0.0f) {                        // anchor (minority positive)
                float pred = sv;
                u64 key = (((u64)__float_as_uint(pred)) << 32) | (u32)i;
                int r = -1;
                #pragma unroll
                for (int q2 = 0; q2 < 4; ++q2) if (fk[q2] == key) r = q2;
                float dpos = 0.0f;
                if (r < 0) {
                    for (int j = 0; j < m; ++j) dpos += fabsf(pred - pv[j]);
                } else {
                    int cnt = 0;
                    #pragma unroll
                    for (int j = 0; j < 4; ++j) {
                        if (j != r && cnt < m) { dpos += fabsf(pred - pv[j]); cnt++; }
                    }
                }
                float dneg = 0.0f;
                for (int l = 0; l < nn; ++l) dneg += fabsf(pred - fn[l]);
                dp += (double)nn * (double)dpos;
                dn += (double)m  * (double)dneg;
            }
        }
        #pragma unroll
        for (int off = 32; off > 0; off >>= 1) {
            dp += __shfl_down(dp, off);
            dn += __shfl_down(dn, off);
        }
        if (lane == 0) { lred[w][0] = dp; lred[w][1] = dn; }
        __syncthreads();
        if (tid == 0) {
            dpp[slot] = lred[0][0] + lred[1][0] + lred[2][0] + lred[3][0];
            dnp[slot] = lred[0][1] + lred[1][1] + lred[2][1] + lred[3][1];
        }
        __syncthreads();   // LDS reuse safety if a block ever takes 2 slots
    }
}

// Finalize: one block sums 512 BCE partials + nm per-slot dp/dn, writes out.
// Kernel boundary provides device-wide visibility of k1/k3 plain stores.
__global__ __launch_bounds__(256) void k4_final(
        const double* __restrict__ bcep, const double* __restrict__ dpp,
        const double* __restrict__ dnp, const int* __restrict__ nmin,
        float* __restrict__ out)
{
    const int tid = threadIdx.x;
    const int nm = *nmin;
    double b = bcep[tid] + bcep[tid + 256];
    double dp = 0.0, dn = 0.0;
    for (int i = tid; i < nm; i += 256) { dp += dpp[i]; dn += dnp[i]; }
    #pragma unroll
    for (int off = 32; off > 0; off >>= 1) {
        b  += __shfl_down(b, off);
        dp += __shfl_down(dp, off);
        dn += __shfl_down(dn, off);
    }
    __shared__ double lb[4], lp[4], ln[4];
    int w = tid >> 6, lane = tid & 63;
    if (lane == 0) { lb[w] = b; lp[w] = dp; ln[w] = dn; }
    __syncthreads();
    if (tid == 0) {
        double bce = (lb[0] + lb[1] + lb[2] + lb[3]) / ((double)B_ * (double)C_);
        double crl = (lp[0] + lp[1] + lp[2] + lp[3])
                   - (ln[0] + ln[1] + ln[2] + ln[3]) + 1.0;   // MARGIN
        if (crl < 0.0) crl = 0.0;
        out[0] = (float)(0.001 * crl + 0.999 * bce);          // ALPHA, 1-ALPHA
    }
}

extern "C" void kernel_launch(void* const* d_in, const int* in_sizes, int n_in,
                              void* d_out, int out_size, void* d_ws, size_t ws_size,
                              hipStream_t stream) {
    const float* input  = (const float*)d_in[0];
    const float* target = (const float*)d_in[1];
    // d_in[2] (X) does not affect the reference output.
    float* out = (float*)d_out;
    char* ws = (char*)d_ws;

    int*    nmin   = (int*)   (ws + OFF_NMIN);
    int*    counts = (int*)   (ws + OFF_COUNTS);
    int*    mlist  = (int*)   (ws + OFF_MLIST);
    double* bcep   = (double*)(ws + OFF_BCEP);
    double* dpp    = (double*)(ws + OFF_DPP);
    double* dnp    = (double*)(ws + OFF_DNP);

    hipMemsetAsync(ws, 0, ZERO_BYTES, stream);   // nmin + counts

    k1_bce_counts<<<dim3(NXB, NCH), 256, 0, stream>>>(input, target, counts, bcep);
    k2_minority<<<C_ / 4, 256, 0, stream>>>(counts, mlist, nmin);
    k3_anchor<<<K3G, 256, 0, stream>>>(input, target, counts, mlist, nmin, dpp, dnp);
    k4_final<<<1, 256, 0, stream>>>(bcep, dpp, dnp, nmin, out);
}